// Round 7
// baseline (48.818 us; speedup 1.0000x reference)
//
#include <hip/hip_runtime.h>
#include <math.h>

#define E_N 40000
#define D_N 200
#define L_N 100
#define K_N 300
#define B_N 32

typedef float  f32x4 __attribute__((ext_vector_type(4)));
typedef short  s16x8 __attribute__((ext_vector_type(8)));

// ws layout (f32 units) — unchanged from round 4/6:
//  sh  [100][32] @ 0      r_l*(num_lit[e1_b,l]-c_l)
//  w   [100][32] @ 3200   nf_w[rel_b,l]
//  nr  [100]     @ 6400   -r_l,  r_l = sqrt(log2e/var_l)
//  s0  [32]      @ 6500   q[b,:].b_lit   (pad to 6532)
//  pA  u16[2][10][64][8] @ 6532   p in MFMA A-frag layout, bf16, zero-pad k>=300
#define WS_SH 0
#define WS_W  3200
#define WS_NR 6400
#define WS_S0 6500
#define WS_PA 6532

// smem layout (f32 units), per-block (single mt half):
//  shT [100][16] @ 0     wT [100][16] @ 1600   nr @ 3200   s0m @ 3300
//  cbuf [2][64][4] @ 3316                      total 3828 f32 = 15312 B
#define SM_W    1600
#define SM_NR   3200
#define SM_CB   3316
#define SM_TOT  3828

__device__ inline float fast_exp2(float x) {
#if __has_builtin(__builtin_amdgcn_exp2f)
    return __builtin_amdgcn_exp2f(x);
#else
    return exp2f(x);
#endif
}
__device__ inline float fast_rcp(float x) {
#if __has_builtin(__builtin_amdgcn_rcpf)
    return __builtin_amdgcn_rcpf(x);
#else
    return 1.0f / x;
#endif
}
__device__ inline ushort f2bf(float f) {        // RNE f32->bf16 (round-2-proven)
    uint u = __builtin_bit_cast(uint, f);
    u += 0x7fffu + ((u >> 16) & 1u);
    return (ushort)(u >> 16);
}
__device__ inline s16x8 pack_bf8(f32x4 lo, f32x4 hi) {   // round-2-proven path
    s16x8 bb;
    bb[0] = (short)f2bf(lo[0]); bb[1] = (short)f2bf(lo[1]);
    bb[2] = (short)f2bf(lo[2]); bb[3] = (short)f2bf(lo[3]);
    bb[4] = (short)f2bf(hi[0]); bb[5] = (short)f2bf(hi[1]);
    bb[6] = (short)f2bf(hi[2]); bb[7] = (short)f2bf(hi[3]);
    return bb;
}

__global__ __launch_bounds__(320) void prep_kernel(
    const int* __restrict__ e1, const int* __restrict__ rel,
    const float* __restrict__ emb_e, const float* __restrict__ emb_rel,
    const float* __restrict__ num_lit, const float* __restrict__ num_lit_norm,
    const float* __restrict__ W, const float* __restrict__ b_lit,
    const float* __restrict__ c, const float* __restrict__ var,
    const float* __restrict__ nf_w, float* __restrict__ ws)
{
    const int b = blockIdx.x;
    const int t = threadIdx.x;
    __shared__ float q[D_N];
    const int e1b = e1[b];
    const int rb  = rel[b];

    if (t < D_N) {
        const float* wr = W + t * K_N;
        const float* er = emb_e + (long)e1b * D_N;
        const float* nl = num_lit_norm + (long)e1b * L_N;
        float s0_ = b_lit[t], s1_ = 0.f, s2_ = 0.f, s3_ = 0.f;
        for (int k = 0; k < D_N; k += 4) {
            s0_ += er[k+0] * wr[k+0]; s1_ += er[k+1] * wr[k+1];
            s2_ += er[k+2] * wr[k+2]; s3_ += er[k+3] * wr[k+3];
        }
        for (int k = 0; k < L_N; k += 4) {
            s0_ += nl[k+0] * wr[D_N+k+0]; s1_ += nl[k+1] * wr[D_N+k+1];
            s2_ += nl[k+2] * wr[D_N+k+2]; s3_ += nl[k+3] * wr[D_N+k+3];
        }
        q[t] = ((s0_ + s1_) + (s2_ + s3_)) * emb_rel[rb * D_N + t];
    }
    __syncthreads();

    {   // p[b,k] = sum_d q[d]*W[d,k]  -> bf16, A-frag layout
        float pk = 0.f;
        if (t < K_N) {
            float a0 = 0.f, a1 = 0.f, a2 = 0.f, a3 = 0.f;
            for (int d = 0; d < D_N; d += 4) {
                a0 += q[d+0] * W[(d+0) * K_N + t];
                a1 += q[d+1] * W[(d+1) * K_N + t];
                a2 += q[d+2] * W[(d+2) * K_N + t];
                a3 += q[d+3] * W[(d+3) * K_N + t];
            }
            pk = (a0 + a1) + (a2 + a3);
        }
        const int s  = t >> 5;
        const int g  = (t >> 3) & 3;
        const int j  = t & 7;
        const int mt = b >> 4;
        const int ln = (g << 4) | (b & 15);
        ushort* pa = (ushort*)(ws + WS_PA);
        pa[((mt * 10 + s) * 64 + ln) * 8 + j] = f2bf(pk);
    }

    if (t < L_N) {
        const float r = sqrtf(1.4426950408889634f / var[t]);
        ws[WS_SH + t * 32 + b] = r * (num_lit[(long)e1b * L_N + t] - c[t]);
        ws[WS_W  + t * 32 + b] = nf_w[rb * L_N + t];
        if (b == 0) ws[WS_NR + t] = -r;
    }
    if (t == 300) {
        float s = 0.f;
        for (int d = 0; d < D_N; ++d) s += q[d] * b_lit[d];
        ws[WS_S0 + b] = s;
    }
}

// Block = 2 tiles (same mt) x 2 l/K-halves. 2500 blocks, 10000 waves.
__global__ __launch_bounds__(256, 4) void score_kernel(
    const float* __restrict__ emb_e, const float* __restrict__ num_lit,
    const float* __restrict__ num_lit_norm, const float* __restrict__ ws,
    float* __restrict__ out)
{
    __shared__ float smem[SM_TOT];

    const int lane = threadIdx.x & 63;
    const int wv   = threadIdx.x >> 6;
    const int wti  = wv & 1;                   // tile within block
    const int h    = wv >> 1;                  // l/K half
    const int mt   = blockIdx.x & 1;
    const int egp  = blockIdx.x >> 1;          // [0, 1250)
    const int eg   = egp * 2 + wti;            // [0, 2500)
    const int er   = lane & 15;
    const int g    = lane >> 4;
    const int e    = eg * 16 + er;
    const int mt4  = mt * 4;

    // ---- stage this mt-half's tables into LDS (829 f32x4); barrier deferred
    {
        const f32x4* s4 = (const f32x4*)ws;
        f32x4* d4 = (f32x4*)smem;
        for (int i = threadIdx.x; i < 829; i += 256) {
            int src;
            if (i < 400) {                                   // shT[l][16]
                src = (i >> 2) * 8 + mt4 + (i & 3);          // WS_SH/4 = 0
            } else if (i < 800) {                            // wT[l][16]
                const int ii = i - 400;
                src = 800 + (ii >> 2) * 8 + mt4 + (ii & 3);  // WS_W/4 = 800
            } else if (i < 825) {                            // nr
                src = 1600 + (i - 800);                      // WS_NR/4 = 1600
            } else {                                         // s0 (mt half)
                src = 1625 + mt4 + (i - 825);                // WS_S0/4 = 1625
            }
            d4[i] = s4[src];
        }
    }

    // ---- acc init: h=0 carries the bias term (16B broadcast, L2-hot) ----
    f32x4 acc = {0.f, 0.f, 0.f, 0.f};
    if (h == 0) acc = *(const f32x4*)(ws + WS_S0 + mt * 16 + 4 * g);

    // ---- A fragments for this K-half: global -> registers ----
    s16x8 afr[5];
    {
        const s16x8* pAg = (const s16x8*)(ws + WS_PA);
#pragma unroll
        for (int i = 0; i < 5; ++i) afr[i] = pAg[(mt * 10 + h * 5 + i) * 64 + lane];
    }

    const float* embr = emb_e        + (long)e * D_N;
    const float* litn = num_lit_norm + (long)e * L_N;

    // ---- score_l via MFMA, K-steps [5h, 5h+5) ----
#pragma unroll
    for (int i = 0; i < 4; ++i) {
        const int k0 = 32 * (h * 5 + i) + 8 * g;
        const float* bp = (k0 < 200) ? (embr + k0) : (litn + (k0 - 200));
        f32x4 lo = *(const f32x4*)bp;
        f32x4 hi = *(const f32x4*)(bp + 4);
        acc = __builtin_amdgcn_mfma_f32_16x16x32_bf16(afr[i], pack_bf8(lo, hi), acc, 0, 0, 0);
    }
    if (h == 0) {       // step s=4: k0 = 128+8g, pure embr
        const int k0 = 128 + 8 * g;
        f32x4 lo = *(const f32x4*)(embr + k0);
        f32x4 hi = *(const f32x4*)(embr + k0 + 4);
        acc = __builtin_amdgcn_mfma_f32_16x16x32_bf16(afr[4], pack_bf8(lo, hi), acc, 0, 0, 0);
    } else {            // step s=9: k = 288..319 (real lit 88..99; A zero-padded k>=300)
        f32x4 z = {0.f, 0.f, 0.f, 0.f};
        f32x4 lo = z, hi = z;
        if (g == 0)      { lo = *(const f32x4*)(litn + 88); hi = *(const f32x4*)(litn + 92); }
        else if (g == 1) { lo = *(const f32x4*)(litn + 96); }
        acc = __builtin_amdgcn_mfma_f32_16x16x32_bf16(afr[4], pack_bf8(lo, hi), acc, 0, 0, 0);
    }

    __syncthreads();    // LDS tables now needed

    const float* shT = smem;
    const float* wT  = smem + SM_W;
    const f32x4* n4  = (const f32x4*)(smem + SM_NR);

    // ---- score_n: RBF, lc in [13h, h?25:13), 2-deep mrow prefetch ----
    const int lc0 = h ? 13 : 0;
    const int lcE = h ? 25 : 13;
    const f32x4* m4 = (const f32x4*)(num_lit + (long)e * L_N);
    f32x4 mv_a = m4[lc0];
    f32x4 mv_b = m4[lc0 + 1];
    for (int lc = lc0; lc < lcE; ++lc) {
        const f32x4 mv = mv_a;
        mv_a = mv_b;
        if (lc + 2 < lcE) mv_b = m4[lc + 2];
        f32x4 nv = n4[lc];
#pragma unroll
        for (int ll = 0; ll < 4; ++ll) {
            const int l = lc * 4 + ll;
            const float rm = nv[ll] * mv[ll];
            f32x4 s4v = *(const f32x4*)(shT + l * 16 + 4 * g);
            f32x4 w4v = *(const f32x4*)(wT  + l * 16 + 4 * g);
#pragma unroll
            for (int j = 0; j < 4; ++j) {
                const float u = rm + s4v[j];
                acc[j] = fmaf(fast_exp2(-(u * u)), w4v[j], acc[j]);
            }
        }
    }

    // ---- combine halves + sigmoid + store ----
    float* cbuf = smem + SM_CB;
    if (h) {
        *(f32x4*)(cbuf + (wti * 64 + lane) * 4) = acc;
    }
    __syncthreads();
    if (!h) {
        const f32x4 o = *(const f32x4*)(cbuf + (wti * 64 + lane) * 4);
#pragma unroll
        for (int j = 0; j < 4; ++j) {
            const float v = acc[j] + o[j];
            const float z = fast_exp2(v * -1.4426950408889634f);
            out[(long)(mt * 16 + 4 * g + j) * E_N + e] = fast_rcp(1.0f + z);
        }
    }
}

extern "C" void kernel_launch(void* const* d_in, const int* in_sizes, int n_in,
                              void* d_out, int out_size, void* d_ws, size_t ws_size,
                              hipStream_t stream) {
    const int*   e1       = (const int*)d_in[0];
    const int*   rel      = (const int*)d_in[1];
    const float* emb_e    = (const float*)d_in[2];
    const float* emb_rel  = (const float*)d_in[3];
    const float* num_lit  = (const float*)d_in[4];
    const float* num_lit_norm = (const float*)d_in[5];
    const float* W_lit    = (const float*)d_in[6];
    const float* b_lit    = (const float*)d_in[7];
    const float* c        = (const float*)d_in[8];
    const float* var      = (const float*)d_in[9];
    const float* nf_w     = (const float*)d_in[10];
    float* out = (float*)d_out;
    float* ws  = (float*)d_ws;

    hipLaunchKernelGGL(prep_kernel, dim3(B_N), dim3(320), 0, stream,
                       e1, rel, emb_e, emb_rel, num_lit, num_lit_norm,
                       W_lit, b_lit, c, var, nf_w, ws);
    hipLaunchKernelGGL(score_kernel, dim3(2500), dim3(256), 0, stream,
                       emb_e, num_lit, num_lit_norm, ws, out);
}

// Round 9
// 46.580 us; speedup vs baseline: 1.0480x; 1.0480x over previous
//
#include <hip/hip_runtime.h>
#include <math.h>

#define E_N 40000
#define D_N 200
#define L_N 100
#define K_N 300
#define B_N 32

typedef float  f32x4 __attribute__((ext_vector_type(4)));
typedef short  s16x8 __attribute__((ext_vector_type(8)));

// ws layout (f32 units) — unchanged:
//  sh  [100][32] @ 0      r_l*(num_lit[e1_b,l]-c_l)
//  w   [100][32] @ 3200   nf_w[rel_b,l]
//  nr  [100]     @ 6400   -r_l,  r_l = sqrt(log2e/var_l)
//  s0  [32]      @ 6500   q[b,:].b_lit   (pad to 6532)
//  pA  u16[2][10][64][8] @ 6532   p in MFMA A-frag layout, bf16, zero-pad k>=300
#define WS_SH 0
#define WS_W  3200
#define WS_NR 6400
#define WS_S0 6500
#define WS_PA 6532

// smem: straight copy of tables (6532 f32 = 1633 f32x4) + cbuf[2][64][4] @ 6532
#define SM_CB  6532
#define SM_TOT 7044

__device__ inline float fast_exp2(float x) {
#if __has_builtin(__builtin_amdgcn_exp2f)
    return __builtin_amdgcn_exp2f(x);
#else
    return exp2f(x);
#endif
}
__device__ inline float fast_rcp(float x) {
#if __has_builtin(__builtin_amdgcn_rcpf)
    return __builtin_amdgcn_rcpf(x);
#else
    return 1.0f / x;
#endif
}
__device__ inline ushort f2bf(float f) {        // RNE f32->bf16 (round-2-proven)
    uint u = __builtin_bit_cast(uint, f);
    u += 0x7fffu + ((u >> 16) & 1u);
    return (ushort)(u >> 16);
}
__device__ inline s16x8 pack_bf8(f32x4 lo, f32x4 hi) {   // round-2-proven path
    s16x8 bb;
    bb[0] = (short)f2bf(lo[0]); bb[1] = (short)f2bf(lo[1]);
    bb[2] = (short)f2bf(lo[2]); bb[3] = (short)f2bf(lo[3]);
    bb[4] = (short)f2bf(hi[0]); bb[5] = (short)f2bf(hi[1]);
    bb[6] = (short)f2bf(hi[2]); bb[7] = (short)f2bf(hi[3]);
    return bb;
}

__global__ __launch_bounds__(320) void prep_kernel(
    const int* __restrict__ e1, const int* __restrict__ rel,
    const float* __restrict__ emb_e, const float* __restrict__ emb_rel,
    const float* __restrict__ num_lit, const float* __restrict__ num_lit_norm,
    const float* __restrict__ W, const float* __restrict__ b_lit,
    const float* __restrict__ c, const float* __restrict__ var,
    const float* __restrict__ nf_w, float* __restrict__ ws)
{
    const int b = blockIdx.x;
    const int t = threadIdx.x;
    __shared__ float q[D_N];
    const int e1b = e1[b];
    const int rb  = rel[b];

    if (t < D_N) {
        const float* wr = W + t * K_N;
        const float* er = emb_e + (long)e1b * D_N;
        const float* nl = num_lit_norm + (long)e1b * L_N;
        float s0_ = b_lit[t], s1_ = 0.f, s2_ = 0.f, s3_ = 0.f;
        for (int k = 0; k < D_N; k += 4) {
            s0_ += er[k+0] * wr[k+0]; s1_ += er[k+1] * wr[k+1];
            s2_ += er[k+2] * wr[k+2]; s3_ += er[k+3] * wr[k+3];
        }
        for (int k = 0; k < L_N; k += 4) {
            s0_ += nl[k+0] * wr[D_N+k+0]; s1_ += nl[k+1] * wr[D_N+k+1];
            s2_ += nl[k+2] * wr[D_N+k+2]; s3_ += nl[k+3] * wr[D_N+k+3];
        }
        q[t] = ((s0_ + s1_) + (s2_ + s3_)) * emb_rel[rb * D_N + t];
    }
    __syncthreads();

    {   // p[b,k] = sum_d q[d]*W[d,k]  -> bf16, A-frag layout
        float pk = 0.f;
        if (t < K_N) {
            float a0 = 0.f, a1 = 0.f, a2 = 0.f, a3 = 0.f;
            for (int d = 0; d < D_N; d += 4) {
                a0 += q[d+0] * W[(d+0) * K_N + t];
                a1 += q[d+1] * W[(d+1) * K_N + t];
                a2 += q[d+2] * W[(d+2) * K_N + t];
                a3 += q[d+3] * W[(d+3) * K_N + t];
            }
            pk = (a0 + a1) + (a2 + a3);
        }
        const int s  = t >> 5;
        const int g  = (t >> 3) & 3;
        const int j  = t & 7;
        const int mt = b >> 4;
        const int ln = (g << 4) | (b & 15);
        ushort* pa = (ushort*)(ws + WS_PA);
        pa[((mt * 10 + s) * 64 + ln) * 8 + j] = f2bf(pk);
    }

    if (t < L_N) {
        const float r = sqrtf(1.4426950408889634f / var[t]);
        ws[WS_SH + t * 32 + b] = r * (num_lit[(long)e1b * L_N + t] - c[t]);
        ws[WS_W  + t * 32 + b] = nf_w[rb * L_N + t];
        if (b == 0) ws[WS_NR + t] = -r;
    }
    if (t == 300) {
        float s = 0.f;
        for (int d = 0; d < D_N; ++d) s += q[d] * b_lit[d];
        ws[WS_S0 + b] = s;
    }
}

// Block = ONE e-group (16 e-rows); waves = (mt, h). 2500 blocks, 10000 waves.
// Both mt-readers of each e-row share the block -> no duplicate HBM fetch.
__global__ __launch_bounds__(256, 4) void score_kernel(
    const float* __restrict__ emb_e, const float* __restrict__ num_lit,
    const float* __restrict__ num_lit_norm, const float* __restrict__ ws,
    float* __restrict__ out)
{
    __shared__ float smem[SM_TOT];

    const int lane = threadIdx.x & 63;
    const int wv   = threadIdx.x >> 6;
    const int mt   = wv & 1;                   // b-half
    const int h    = wv >> 1;                  // l/K half
    const int eg   = blockIdx.x;               // [0, 2500)
    const int er   = lane & 15;
    const int g    = lane >> 4;
    const int e    = eg * 16 + er;
    const int b0   = mt * 16 + 4 * g;

    // ---- stage tables to LDS (1633 f32x4, straight copy), immediate barrier
    //      (round-4-proven position) ----
    {
        const f32x4* s4 = (const f32x4*)ws;
        f32x4* d4 = (f32x4*)smem;
        for (int i = threadIdx.x; i < 1633; i += 256) d4[i] = s4[i];
    }
    __syncthreads();

    // ---- acc init: h=0 carries the bias term (16B broadcast, L2-hot) ----
    f32x4 acc = {0.f, 0.f, 0.f, 0.f};
    if (h == 0) acc = *(const f32x4*)(ws + WS_S0 + b0);

    // ---- A fragments for this (mt, K-half): global -> registers ----
    s16x8 afr[5];
    {
        const s16x8* pAg = (const s16x8*)(ws + WS_PA);
#pragma unroll
        for (int i = 0; i < 5; ++i) afr[i] = pAg[(mt * 10 + h * 5 + i) * 64 + lane];
    }

    const float* embr = emb_e        + (long)e * D_N;
    const float* litn = num_lit_norm + (long)e * L_N;

    // ---- score_l via MFMA, K-steps [5h, 5h+5), loads in-loop (round-7 form) ----
#pragma unroll
    for (int i = 0; i < 4; ++i) {
        const int k0 = 32 * (h * 5 + i) + 8 * g;
        const float* bp = (k0 < 200) ? (embr + k0) : (litn + (k0 - 200));
        f32x4 lo = *(const f32x4*)bp;
        f32x4 hi = *(const f32x4*)(bp + 4);
        acc = __builtin_amdgcn_mfma_f32_16x16x32_bf16(afr[i], pack_bf8(lo, hi), acc, 0, 0, 0);
    }
    if (h == 0) {       // step s=4: k0 = 128+8g, pure embr
        const int k0 = 128 + 8 * g;
        f32x4 lo = *(const f32x4*)(embr + k0);
        f32x4 hi = *(const f32x4*)(embr + k0 + 4);
        acc = __builtin_amdgcn_mfma_f32_16x16x32_bf16(afr[4], pack_bf8(lo, hi), acc, 0, 0, 0);
    } else {            // step s=9: k = 288..319 (real lit 88..99; A zero-pads k>=300)
        f32x4 z = {0.f, 0.f, 0.f, 0.f};
        f32x4 lo = z, hi = z;
        if (g == 0)      { lo = *(const f32x4*)(litn + 88); hi = *(const f32x4*)(litn + 92); }
        else if (g == 1) { lo = *(const f32x4*)(litn + 96); }
        acc = __builtin_amdgcn_mfma_f32_16x16x32_bf16(afr[4], pack_bf8(lo, hi), acc, 0, 0, 0);
    }

    // ---- score_n: RBF, lc in [13h, h?25:13), 2-deep mrow prefetch (round-7 form) ----
    const int lc0 = h ? 13 : 0;
    const int lcE = h ? 25 : 13;
    const f32x4* m4 = (const f32x4*)(num_lit + (long)e * L_N);
    f32x4 mv_a = m4[lc0];
    f32x4 mv_b = m4[lc0 + 1];
    for (int lc = lc0; lc < lcE; ++lc) {
        const f32x4 mv = mv_a;
        mv_a = mv_b;
        if (lc + 2 < lcE) mv_b = m4[lc + 2];
        const f32x4 nv = *(const f32x4*)(smem + WS_NR + lc * 4);
#pragma unroll
        for (int ll = 0; ll < 4; ++ll) {
            const int l = lc * 4 + ll;
            const float rm = nv[ll] * mv[ll];
            f32x4 s4v = *(const f32x4*)(smem + WS_SH + l * 32 + b0);
            f32x4 w4v = *(const f32x4*)(smem + WS_W  + l * 32 + b0);
#pragma unroll
            for (int j = 0; j < 4; ++j) {
                const float u = rm + s4v[j];
                acc[j] = fmaf(fast_exp2(-(u * u)), w4v[j], acc[j]);
            }
        }
    }

    // ---- combine halves + sigmoid + store (round-7-proven pattern) ----
    float* cbuf = smem + SM_CB;
    if (h) {
        *(f32x4*)(cbuf + (mt * 64 + lane) * 4) = acc;
    }
    __syncthreads();
    if (!h) {
        const f32x4 o = *(const f32x4*)(cbuf + (mt * 64 + lane) * 4);
#pragma unroll
        for (int j = 0; j < 4; ++j) {
            const float v = acc[j] + o[j];
            const float z = fast_exp2(v * -1.4426950408889634f);
            out[(long)(b0 + j) * E_N + e] = fast_rcp(1.0f + z);
        }
    }
}

extern "C" void kernel_launch(void* const* d_in, const int* in_sizes, int n_in,
                              void* d_out, int out_size, void* d_ws, size_t ws_size,
                              hipStream_t stream) {
    const int*   e1       = (const int*)d_in[0];
    const int*   rel      = (const int*)d_in[1];
    const float* emb_e    = (const float*)d_in[2];
    const float* emb_rel  = (const float*)d_in[3];
    const float* num_lit  = (const float*)d_in[4];
    const float* num_lit_norm = (const float*)d_in[5];
    const float* W_lit    = (const float*)d_in[6];
    const float* b_lit    = (const float*)d_in[7];
    const float* c        = (const float*)d_in[8];
    const float* var      = (const float*)d_in[9];
    const float* nf_w     = (const float*)d_in[10];
    float* out = (float*)d_out;
    float* ws  = (float*)d_ws;

    hipLaunchKernelGGL(prep_kernel, dim3(B_N), dim3(320), 0, stream,
                       e1, rel, emb_e, emb_rel, num_lit, num_lit_norm,
                       W_lit, b_lit, c, var, nf_w, ws);
    hipLaunchKernelGGL(score_kernel, dim3(2500), dim3(256), 0, stream,
                       emb_e, num_lit, num_lit_norm, ws, out);
}

// Round 10
// 45.998 us; speedup vs baseline: 1.0613x; 1.0126x over previous
//
#include <hip/hip_runtime.h>
#include <math.h>

#define E_N 40000
#define D_N 200
#define L_N 100
#define K_N 300
#define B_N 32

typedef float  f32x4 __attribute__((ext_vector_type(4)));
typedef short  s16x8 __attribute__((ext_vector_type(8)));

// ws layout (f32 units) — unchanged:
//  sh  [100][32] @ 0      r_l*(num_lit[e1_b,l]-c_l)
//  w   [100][32] @ 3200   nf_w[rel_b,l]
//  nr  [100]     @ 6400   -r_l,  r_l = sqrt(log2e/var_l)
//  s0  [32]      @ 6500   q[b,:].b_lit   (pad to 6532)
//  pA  u16[2][10][64][8] @ 6532   p in MFMA A-frag layout, bf16, zero-pad k>=300
#define WS_SH 0
#define WS_W  3200
#define WS_NR 6400
#define WS_S0 6500
#define WS_PA 6532

// smem: tables copy (6532 f32) + cbuf[2 tile][2 mt][64 lane][4] @ 6532 (1024 f32)
#define SM_CB  6532
#define SM_TOT 7556

__device__ inline float fast_exp2(float x) {
#if __has_builtin(__builtin_amdgcn_exp2f)
    return __builtin_amdgcn_exp2f(x);
#else
    return exp2f(x);
#endif
}
__device__ inline float fast_rcp(float x) {
#if __has_builtin(__builtin_amdgcn_rcpf)
    return __builtin_amdgcn_rcpf(x);
#else
    return 1.0f / x;
#endif
}
__device__ inline ushort f2bf(float f) {        // RNE f32->bf16 (round-2-proven)
    uint u = __builtin_bit_cast(uint, f);
    u += 0x7fffu + ((u >> 16) & 1u);
    return (ushort)(u >> 16);
}
__device__ inline s16x8 pack_bf8(f32x4 lo, f32x4 hi) {   // round-2-proven path
    s16x8 bb;
    bb[0] = (short)f2bf(lo[0]); bb[1] = (short)f2bf(lo[1]);
    bb[2] = (short)f2bf(lo[2]); bb[3] = (short)f2bf(lo[3]);
    bb[4] = (short)f2bf(hi[0]); bb[5] = (short)f2bf(hi[1]);
    bb[6] = (short)f2bf(hi[2]); bb[7] = (short)f2bf(hi[3]);
    return bb;
}

__global__ __launch_bounds__(320) void prep_kernel(
    const int* __restrict__ e1, const int* __restrict__ rel,
    const float* __restrict__ emb_e, const float* __restrict__ emb_rel,
    const float* __restrict__ num_lit, const float* __restrict__ num_lit_norm,
    const float* __restrict__ W, const float* __restrict__ b_lit,
    const float* __restrict__ c, const float* __restrict__ var,
    const float* __restrict__ nf_w, float* __restrict__ ws)
{
    const int b = blockIdx.x;
    const int t = threadIdx.x;
    __shared__ float q[D_N];
    const int e1b = e1[b];
    const int rb  = rel[b];

    if (t < D_N) {
        const float* wr = W + t * K_N;
        const float* er = emb_e + (long)e1b * D_N;
        const float* nl = num_lit_norm + (long)e1b * L_N;
        float s0_ = b_lit[t], s1_ = 0.f, s2_ = 0.f, s3_ = 0.f;
        for (int k = 0; k < D_N; k += 4) {
            s0_ += er[k+0] * wr[k+0]; s1_ += er[k+1] * wr[k+1];
            s2_ += er[k+2] * wr[k+2]; s3_ += er[k+3] * wr[k+3];
        }
        for (int k = 0; k < L_N; k += 4) {
            s0_ += nl[k+0] * wr[D_N+k+0]; s1_ += nl[k+1] * wr[D_N+k+1];
            s2_ += nl[k+2] * wr[D_N+k+2]; s3_ += nl[k+3] * wr[D_N+k+3];
        }
        q[t] = ((s0_ + s1_) + (s2_ + s3_)) * emb_rel[rb * D_N + t];
    }
    __syncthreads();

    {   // p[b,k] = sum_d q[d]*W[d,k]  -> bf16, A-frag layout
        float pk = 0.f;
        if (t < K_N) {
            float a0 = 0.f, a1 = 0.f, a2 = 0.f, a3 = 0.f;
            for (int d = 0; d < D_N; d += 4) {
                a0 += q[d+0] * W[(d+0) * K_N + t];
                a1 += q[d+1] * W[(d+1) * K_N + t];
                a2 += q[d+2] * W[(d+2) * K_N + t];
                a3 += q[d+3] * W[(d+3) * K_N + t];
            }
            pk = (a0 + a1) + (a2 + a3);
        }
        const int s  = t >> 5;
        const int g  = (t >> 3) & 3;
        const int j  = t & 7;
        const int mt = b >> 4;
        const int ln = (g << 4) | (b & 15);
        ushort* pa = (ushort*)(ws + WS_PA);
        pa[((mt * 10 + s) * 64 + ln) * 8 + j] = f2bf(pk);
    }

    if (t < L_N) {
        const float r = sqrtf(1.4426950408889634f / var[t]);
        ws[WS_SH + t * 32 + b] = r * (num_lit[(long)e1b * L_N + t] - c[t]);
        ws[WS_W  + t * 32 + b] = nf_w[rb * L_N + t];
        if (b == 0) ws[WS_NR + t] = -r;
    }
    if (t == 300) {
        float s = 0.f;
        for (int d = 0; d < D_N; ++d) s += q[d] * b_lit[d];
        ws[WS_S0 + b] = s;
    }
}

// Block = 32 e-rows (two 16-e MFMA tiles); waves = (mt, h). 1250 blocks, 5000 waves.
// Each wave covers 32e x 16b: sh/w LDS reads amortized over 2 e-tiles (halves
// total ds_read_b128 count vs round 9 — the cross-round invariant at ~44us).
__global__ __launch_bounds__(256, 3) void score_kernel(
    const float* __restrict__ emb_e, const float* __restrict__ num_lit,
    const float* __restrict__ num_lit_norm, const float* __restrict__ ws,
    float* __restrict__ out)
{
    __shared__ float smem[SM_TOT];

    const int lane = threadIdx.x & 63;
    const int wv   = threadIdx.x >> 6;
    const int mt   = wv & 1;                   // b-half
    const int h    = wv >> 1;                  // l/K half
    const int er   = lane & 15;
    const int g    = lane >> 4;
    const int ea   = blockIdx.x * 32 + er;         // e-tile 0
    const int eb   = ea + 16;                      // e-tile 1
    const int b0   = mt * 16 + 4 * g;

    // ---- stage tables to LDS (1633 f32x4, straight copy), immediate barrier ----
    {
        const f32x4* s4 = (const f32x4*)ws;
        f32x4* d4 = (f32x4*)smem;
        for (int i = threadIdx.x; i < 1633; i += 256) d4[i] = s4[i];
    }
    __syncthreads();

    // ---- acc init: h=0 carries the bias term (depends only on b) ----
    f32x4 acc_a = {0.f, 0.f, 0.f, 0.f};
    f32x4 acc_b = {0.f, 0.f, 0.f, 0.f};
    if (h == 0) {
        acc_a = *(const f32x4*)(ws + WS_S0 + b0);
        acc_b = acc_a;
    }

    // ---- A fragments for this (mt, K-half): shared by both e-tiles ----
    s16x8 afr[5];
    {
        const s16x8* pAg = (const s16x8*)(ws + WS_PA);
#pragma unroll
        for (int i = 0; i < 5; ++i) afr[i] = pAg[(mt * 10 + h * 5 + i) * 64 + lane];
    }

    const float* embrA = emb_e        + (long)ea * D_N;
    const float* litnA = num_lit_norm + (long)ea * L_N;
    const float* embrB = emb_e        + (long)eb * D_N;
    const float* litnB = num_lit_norm + (long)eb * L_N;

    // ---- score_l via MFMA, K-steps [5h, 5h+5), two e-tiles ----
#pragma unroll
    for (int i = 0; i < 4; ++i) {
        const int k0 = 32 * (h * 5 + i) + 8 * g;
        const float* bpA = (k0 < 200) ? (embrA + k0) : (litnA + (k0 - 200));
        const float* bpB = (k0 < 200) ? (embrB + k0) : (litnB + (k0 - 200));
        f32x4 loA = *(const f32x4*)bpA;
        f32x4 hiA = *(const f32x4*)(bpA + 4);
        f32x4 loB = *(const f32x4*)bpB;
        f32x4 hiB = *(const f32x4*)(bpB + 4);
        acc_a = __builtin_amdgcn_mfma_f32_16x16x32_bf16(afr[i], pack_bf8(loA, hiA), acc_a, 0, 0, 0);
        acc_b = __builtin_amdgcn_mfma_f32_16x16x32_bf16(afr[i], pack_bf8(loB, hiB), acc_b, 0, 0, 0);
    }
    if (h == 0) {       // step s=4: k0 = 128+8g, pure embr
        const int k0 = 128 + 8 * g;
        f32x4 loA = *(const f32x4*)(embrA + k0);
        f32x4 hiA = *(const f32x4*)(embrA + k0 + 4);
        f32x4 loB = *(const f32x4*)(embrB + k0);
        f32x4 hiB = *(const f32x4*)(embrB + k0 + 4);
        acc_a = __builtin_amdgcn_mfma_f32_16x16x32_bf16(afr[4], pack_bf8(loA, hiA), acc_a, 0, 0, 0);
        acc_b = __builtin_amdgcn_mfma_f32_16x16x32_bf16(afr[4], pack_bf8(loB, hiB), acc_b, 0, 0, 0);
    } else {            // step s=9: k = 288..319 (real lit 88..99; A zero-pads k>=300)
        f32x4 z = {0.f, 0.f, 0.f, 0.f};
        f32x4 loA = z, hiA = z, loB = z, hiB = z;
        if (g == 0)      { loA = *(const f32x4*)(litnA + 88); hiA = *(const f32x4*)(litnA + 92);
                           loB = *(const f32x4*)(litnB + 88); hiB = *(const f32x4*)(litnB + 92); }
        else if (g == 1) { loA = *(const f32x4*)(litnA + 96);
                           loB = *(const f32x4*)(litnB + 96); }
        acc_a = __builtin_amdgcn_mfma_f32_16x16x32_bf16(afr[4], pack_bf8(loA, hiA), acc_a, 0, 0, 0);
        acc_b = __builtin_amdgcn_mfma_f32_16x16x32_bf16(afr[4], pack_bf8(loB, hiB), acc_b, 0, 0, 0);
    }

    // ---- score_n: RBF, lc in [13h, h?25:13); 2-deep prefetch per e-row ----
    const int lc0 = h ? 13 : 0;
    const int lcE = h ? 25 : 13;
    const f32x4* m4a = (const f32x4*)(num_lit + (long)ea * L_N);
    const f32x4* m4b = (const f32x4*)(num_lit + (long)eb * L_N);
    f32x4 pa0 = m4a[lc0], pa1 = m4a[lc0 + 1];
    f32x4 pb0 = m4b[lc0], pb1 = m4b[lc0 + 1];
    for (int lc = lc0; lc < lcE; ++lc) {
        const f32x4 mva = pa0; pa0 = pa1;
        const f32x4 mvb = pb0; pb0 = pb1;
        if (lc + 2 < lcE) { pa1 = m4a[lc + 2]; pb1 = m4b[lc + 2]; }
        const f32x4 nv = *(const f32x4*)(smem + WS_NR + lc * 4);
#pragma unroll
        for (int ll = 0; ll < 4; ++ll) {
            const int l = lc * 4 + ll;
            const float rma = nv[ll] * mva[ll];
            const float rmb = nv[ll] * mvb[ll];
            f32x4 s4v = *(const f32x4*)(smem + WS_SH + l * 32 + b0);
            f32x4 w4v = *(const f32x4*)(smem + WS_W  + l * 32 + b0);
#pragma unroll
            for (int j = 0; j < 4; ++j) {
                const float ua = rma + s4v[j];
                const float ub = rmb + s4v[j];
                acc_a[j] = fmaf(fast_exp2(-(ua * ua)), w4v[j], acc_a[j]);
                acc_b[j] = fmaf(fast_exp2(-(ub * ub)), w4v[j], acc_b[j]);
            }
        }
    }

    // ---- combine halves + sigmoid + store (round-9-proven pattern, 2 tiles) ----
    float* cbuf = smem + SM_CB;
    if (h) {
        *(f32x4*)(cbuf + ((0 * 2 + mt) * 64 + lane) * 4) = acc_a;
        *(f32x4*)(cbuf + ((1 * 2 + mt) * 64 + lane) * 4) = acc_b;
    }
    __syncthreads();
    if (!h) {
        const f32x4 oa = *(const f32x4*)(cbuf + ((0 * 2 + mt) * 64 + lane) * 4);
        const f32x4 ob = *(const f32x4*)(cbuf + ((1 * 2 + mt) * 64 + lane) * 4);
#pragma unroll
        for (int j = 0; j < 4; ++j) {
            const float va = acc_a[j] + oa[j];
            const float za = fast_exp2(va * -1.4426950408889634f);
            out[(long)(b0 + j) * E_N + ea] = fast_rcp(1.0f + za);
            const float vb = acc_b[j] + ob[j];
            const float zb = fast_exp2(vb * -1.4426950408889634f);
            out[(long)(b0 + j) * E_N + eb] = fast_rcp(1.0f + zb);
        }
    }
}

extern "C" void kernel_launch(void* const* d_in, const int* in_sizes, int n_in,
                              void* d_out, int out_size, void* d_ws, size_t ws_size,
                              hipStream_t stream) {
    const int*   e1       = (const int*)d_in[0];
    const int*   rel      = (const int*)d_in[1];
    const float* emb_e    = (const float*)d_in[2];
    const float* emb_rel  = (const float*)d_in[3];
    const float* num_lit  = (const float*)d_in[4];
    const float* num_lit_norm = (const float*)d_in[5];
    const float* W_lit    = (const float*)d_in[6];
    const float* b_lit    = (const float*)d_in[7];
    const float* c        = (const float*)d_in[8];
    const float* var      = (const float*)d_in[9];
    const float* nf_w     = (const float*)d_in[10];
    float* out = (float*)d_out;
    float* ws  = (float*)d_ws;

    hipLaunchKernelGGL(prep_kernel, dim3(B_N), dim3(320), 0, stream,
                       e1, rel, emb_e, emb_rel, num_lit, num_lit_norm,
                       W_lit, b_lit, c, var, nf_w, ws);
    hipLaunchKernelGGL(score_kernel, dim3(1250), dim3(256), 0, stream,
                       emb_e, num_lit, num_lit_norm, ws, out);
}

// Round 11
// 44.036 us; speedup vs baseline: 1.1086x; 1.0446x over previous
//
#include <hip/hip_runtime.h>
#include <math.h>

#define E_N 40000
#define D_N 200
#define L_N 100
#define K_N 300
#define B_N 32

typedef float  f32x4 __attribute__((ext_vector_type(4)));
typedef short  s16x8 __attribute__((ext_vector_type(8)));

// ws layout (f32 units) — unchanged:
//  sh  [100][32] @ 0      r_l*(num_lit[e1_b,l]-c_l)
//  w   [100][32] @ 3200   nf_w[rel_b,l]
//  nr  [100]     @ 6400   -r_l,  r_l = sqrt(log2e/var_l)
//  s0  [32]      @ 6500   q[b,:].b_lit   (pad to 6532)
//  pA  u16[2][10][64][8] @ 6532   p in MFMA A-frag layout, bf16, zero-pad k>=300
#define WS_SH 0
#define WS_W  3200
#define WS_NR 6400
#define WS_S0 6500
#define WS_PA 6532

// smem layout (f32): tables copy [0,6532) + mlit[32][100] @ 6532 (3200 f32)
//                    + cbuf[2 tile][2 mt][64 lane][4] @ 9732 (1024 f32)
#define SM_ML  6532
#define SM_CB  9732
#define SM_TOT 10756     // 43024 B

__device__ inline float fast_exp2(float x) {
#if __has_builtin(__builtin_amdgcn_exp2f)
    return __builtin_amdgcn_exp2f(x);
#else
    return exp2f(x);
#endif
}
__device__ inline float fast_rcp(float x) {
#if __has_builtin(__builtin_amdgcn_rcpf)
    return __builtin_amdgcn_rcpf(x);
#else
    return 1.0f / x;
#endif
}
__device__ inline ushort f2bf(float f) {        // RNE f32->bf16 (round-2-proven)
    uint u = __builtin_bit_cast(uint, f);
    u += 0x7fffu + ((u >> 16) & 1u);
    return (ushort)(u >> 16);
}
__device__ inline s16x8 pack_bf8(f32x4 lo, f32x4 hi) {   // round-2-proven path
    s16x8 bb;
    bb[0] = (short)f2bf(lo[0]); bb[1] = (short)f2bf(lo[1]);
    bb[2] = (short)f2bf(lo[2]); bb[3] = (short)f2bf(lo[3]);
    bb[4] = (short)f2bf(hi[0]); bb[5] = (short)f2bf(hi[1]);
    bb[6] = (short)f2bf(hi[2]); bb[7] = (short)f2bf(hi[3]);
    return bb;
}

__global__ __launch_bounds__(320) void prep_kernel(
    const int* __restrict__ e1, const int* __restrict__ rel,
    const float* __restrict__ emb_e, const float* __restrict__ emb_rel,
    const float* __restrict__ num_lit, const float* __restrict__ num_lit_norm,
    const float* __restrict__ W, const float* __restrict__ b_lit,
    const float* __restrict__ c, const float* __restrict__ var,
    const float* __restrict__ nf_w, float* __restrict__ ws)
{
    const int b = blockIdx.x;
    const int t = threadIdx.x;
    __shared__ float q[D_N];
    const int e1b = e1[b];
    const int rb  = rel[b];

    if (t < D_N) {
        const float* wr = W + t * K_N;
        const float* er = emb_e + (long)e1b * D_N;
        const float* nl = num_lit_norm + (long)e1b * L_N;
        float s0_ = b_lit[t], s1_ = 0.f, s2_ = 0.f, s3_ = 0.f;
        for (int k = 0; k < D_N; k += 4) {
            s0_ += er[k+0] * wr[k+0]; s1_ += er[k+1] * wr[k+1];
            s2_ += er[k+2] * wr[k+2]; s3_ += er[k+3] * wr[k+3];
        }
        for (int k = 0; k < L_N; k += 4) {
            s0_ += nl[k+0] * wr[D_N+k+0]; s1_ += nl[k+1] * wr[D_N+k+1];
            s2_ += nl[k+2] * wr[D_N+k+2]; s3_ += nl[k+3] * wr[D_N+k+3];
        }
        q[t] = ((s0_ + s1_) + (s2_ + s3_)) * emb_rel[rb * D_N + t];
    }
    __syncthreads();

    {   // p[b,k] = sum_d q[d]*W[d,k]  -> bf16, A-frag layout
        float pk = 0.f;
        if (t < K_N) {
            float a0 = 0.f, a1 = 0.f, a2 = 0.f, a3 = 0.f;
            for (int d = 0; d < D_N; d += 4) {
                a0 += q[d+0] * W[(d+0) * K_N + t];
                a1 += q[d+1] * W[(d+1) * K_N + t];
                a2 += q[d+2] * W[(d+2) * K_N + t];
                a3 += q[d+3] * W[(d+3) * K_N + t];
            }
            pk = (a0 + a1) + (a2 + a3);
        }
        const int s  = t >> 5;
        const int g  = (t >> 3) & 3;
        const int j  = t & 7;
        const int mt = b >> 4;
        const int ln = (g << 4) | (b & 15);
        ushort* pa = (ushort*)(ws + WS_PA);
        pa[((mt * 10 + s) * 64 + ln) * 8 + j] = f2bf(pk);
    }

    if (t < L_N) {
        const float r = sqrtf(1.4426950408889634f / var[t]);
        ws[WS_SH + t * 32 + b] = r * (num_lit[(long)e1b * L_N + t] - c[t]);
        ws[WS_W  + t * 32 + b] = nf_w[rb * L_N + t];
        if (b == 0) ws[WS_NR + t] = -r;
    }
    if (t == 300) {
        float s = 0.f;
        for (int d = 0; d < D_N; ++d) s += q[d] * b_lit[d];
        ws[WS_S0 + b] = s;
    }
}

// Block = 32 e-rows (two 16-e MFMA tiles); waves = (mt, h). 1250 blocks, 5000 waves.
// NEW vs round 10: the block's 32 num_lit rows are staged to LDS, making the
// RBF loop free of global-memory accesses (the last in-loop latency stream).
__global__ __launch_bounds__(256, 3) void score_kernel(
    const float* __restrict__ emb_e, const float* __restrict__ num_lit,
    const float* __restrict__ num_lit_norm, const float* __restrict__ ws,
    float* __restrict__ out)
{
    __shared__ float smem[SM_TOT];

    const int lane = threadIdx.x & 63;
    const int wv   = threadIdx.x >> 6;
    const int mt   = wv & 1;                   // b-half
    const int h    = wv >> 1;                  // l/K half
    const int er   = lane & 15;
    const int g    = lane >> 4;
    const int ea   = blockIdx.x * 32 + er;         // e-tile 0
    const int eb   = ea + 16;                      // e-tile 1
    const int b0   = mt * 16 + 4 * g;

    // ---- stage tables (1633 f32x4) + this block's 32 num_lit rows (800 f32x4) ----
    {
        const f32x4* s4 = (const f32x4*)ws;
        f32x4* d4 = (f32x4*)smem;
        for (int i = threadIdx.x; i < 1633; i += 256) d4[i] = s4[i];
        const f32x4* ml4 = (const f32x4*)(num_lit + (long)blockIdx.x * 32 * L_N);
        for (int i = threadIdx.x; i < 800; i += 256) d4[1633 + i] = ml4[i];
    }
    __syncthreads();

    // ---- acc init: h=0 carries the bias term (depends only on b) ----
    f32x4 acc_a = {0.f, 0.f, 0.f, 0.f};
    f32x4 acc_b = {0.f, 0.f, 0.f, 0.f};
    if (h == 0) {
        acc_a = *(const f32x4*)(ws + WS_S0 + b0);
        acc_b = acc_a;
    }

    // ---- A fragments for this (mt, K-half): shared by both e-tiles ----
    s16x8 afr[5];
    {
        const s16x8* pAg = (const s16x8*)(ws + WS_PA);
#pragma unroll
        for (int i = 0; i < 5; ++i) afr[i] = pAg[(mt * 10 + h * 5 + i) * 64 + lane];
    }

    const float* embrA = emb_e        + (long)ea * D_N;
    const float* litnA = num_lit_norm + (long)ea * L_N;
    const float* embrB = emb_e        + (long)eb * D_N;
    const float* litnB = num_lit_norm + (long)eb * L_N;

    // ---- score_l via MFMA, K-steps [5h, 5h+5), two e-tiles ----
#pragma unroll
    for (int i = 0; i < 4; ++i) {
        const int k0 = 32 * (h * 5 + i) + 8 * g;
        const float* bpA = (k0 < 200) ? (embrA + k0) : (litnA + (k0 - 200));
        const float* bpB = (k0 < 200) ? (embrB + k0) : (litnB + (k0 - 200));
        f32x4 loA = *(const f32x4*)bpA;
        f32x4 hiA = *(const f32x4*)(bpA + 4);
        f32x4 loB = *(const f32x4*)bpB;
        f32x4 hiB = *(const f32x4*)(bpB + 4);
        acc_a = __builtin_amdgcn_mfma_f32_16x16x32_bf16(afr[i], pack_bf8(loA, hiA), acc_a, 0, 0, 0);
        acc_b = __builtin_amdgcn_mfma_f32_16x16x32_bf16(afr[i], pack_bf8(loB, hiB), acc_b, 0, 0, 0);
    }
    if (h == 0) {       // step s=4: k0 = 128+8g, pure embr
        const int k0 = 128 + 8 * g;
        f32x4 loA = *(const f32x4*)(embrA + k0);
        f32x4 hiA = *(const f32x4*)(embrA + k0 + 4);
        f32x4 loB = *(const f32x4*)(embrB + k0);
        f32x4 hiB = *(const f32x4*)(embrB + k0 + 4);
        acc_a = __builtin_amdgcn_mfma_f32_16x16x32_bf16(afr[4], pack_bf8(loA, hiA), acc_a, 0, 0, 0);
        acc_b = __builtin_amdgcn_mfma_f32_16x16x32_bf16(afr[4], pack_bf8(loB, hiB), acc_b, 0, 0, 0);
    } else {            // step s=9: k = 288..319 (real lit 88..99; A zero-pads k>=300)
        f32x4 z = {0.f, 0.f, 0.f, 0.f};
        f32x4 loA = z, hiA = z, loB = z, hiB = z;
        if (g == 0)      { loA = *(const f32x4*)(litnA + 88); hiA = *(const f32x4*)(litnA + 92);
                           loB = *(const f32x4*)(litnB + 88); hiB = *(const f32x4*)(litnB + 92); }
        else if (g == 1) { loA = *(const f32x4*)(litnA + 96);
                           loB = *(const f32x4*)(litnB + 96); }
        acc_a = __builtin_amdgcn_mfma_f32_16x16x32_bf16(afr[4], pack_bf8(loA, hiA), acc_a, 0, 0, 0);
        acc_b = __builtin_amdgcn_mfma_f32_16x16x32_bf16(afr[4], pack_bf8(loB, hiB), acc_b, 0, 0, 0);
    }

    // ---- score_n: RBF, lc in [13h, h?25:13) — all operands in LDS ----
    const int lc0 = h ? 13 : 0;
    const int lcE = h ? 25 : 13;
    const float* mlA = smem + SM_ML + er * L_N;          // this lane's tile-a row
    const float* mlB = mlA + 16 * L_N;                   // tile-b row
    for (int lc = lc0; lc < lcE; ++lc) {
        const f32x4 mva = *(const f32x4*)(mlA + lc * 4);
        const f32x4 mvb = *(const f32x4*)(mlB + lc * 4);
        const f32x4 nv  = *(const f32x4*)(smem + WS_NR + lc * 4);
#pragma unroll
        for (int ll = 0; ll < 4; ++ll) {
            const int l = lc * 4 + ll;
            const float rma = nv[ll] * mva[ll];
            const float rmb = nv[ll] * mvb[ll];
            f32x4 s4v = *(const f32x4*)(smem + WS_SH + l * 32 + b0);
            f32x4 w4v = *(const f32x4*)(smem + WS_W  + l * 32 + b0);
#pragma unroll
            for (int j = 0; j < 4; ++j) {
                const float ua = rma + s4v[j];
                const float ub = rmb + s4v[j];
                acc_a[j] = fmaf(fast_exp2(-(ua * ua)), w4v[j], acc_a[j]);
                acc_b[j] = fmaf(fast_exp2(-(ub * ub)), w4v[j], acc_b[j]);
            }
        }
    }

    // ---- combine halves + sigmoid + store (round-10-proven pattern) ----
    float* cbuf = smem + SM_CB;
    if (h) {
        *(f32x4*)(cbuf + ((0 * 2 + mt) * 64 + lane) * 4) = acc_a;
        *(f32x4*)(cbuf + ((1 * 2 + mt) * 64 + lane) * 4) = acc_b;
    }
    __syncthreads();
    if (!h) {
        const f32x4 oa = *(const f32x4*)(cbuf + ((0 * 2 + mt) * 64 + lane) * 4);
        const f32x4 ob = *(const f32x4*)(cbuf + ((1 * 2 + mt) * 64 + lane) * 4);
#pragma unroll
        for (int j = 0; j < 4; ++j) {
            const float va = acc_a[j] + oa[j];
            const float za = fast_exp2(va * -1.4426950408889634f);
            out[(long)(b0 + j) * E_N + ea] = fast_rcp(1.0f + za);
            const float vb = acc_b[j] + ob[j];
            const float zb = fast_exp2(vb * -1.4426950408889634f);
            out[(long)(b0 + j) * E_N + eb] = fast_rcp(1.0f + zb);
        }
    }
}

extern "C" void kernel_launch(void* const* d_in, const int* in_sizes, int n_in,
                              void* d_out, int out_size, void* d_ws, size_t ws_size,
                              hipStream_t stream) {
    const int*   e1       = (const int*)d_in[0];
    const int*   rel      = (const int*)d_in[1];
    const float* emb_e    = (const float*)d_in[2];
    const float* emb_rel  = (const float*)d_in[3];
    const float* num_lit  = (const float*)d_in[4];
    const float* num_lit_norm = (const float*)d_in[5];
    const float* W_lit    = (const float*)d_in[6];
    const float* b_lit    = (const float*)d_in[7];
    const float* c        = (const float*)d_in[8];
    const float* var      = (const float*)d_in[9];
    const float* nf_w     = (const float*)d_in[10];
    float* out = (float*)d_out;
    float* ws  = (float*)d_ws;

    hipLaunchKernelGGL(prep_kernel, dim3(B_N), dim3(320), 0, stream,
                       e1, rel, emb_e, emb_rel, num_lit, num_lit_norm,
                       W_lit, b_lit, c, var, nf_w, ws);
    hipLaunchKernelGGL(score_kernel, dim3(1250), dim3(256), 0, stream,
                       emb_e, num_lit, num_lit_norm, ws, out);
}